// Round 7
// baseline (584.916 us; speedup 1.0000x reference)
//
#include <hip/hip_runtime.h>

// ---------------------------------------------------------------------------
// MultiheadSelfAttentionRoPE  (f32 inputs -> **f32 output**)
//   B=2, S=2048, D=2048, H=16, dk=128, causal, RoPE interleaved pairs.
// ROOT CAUSE (r0-r6): d_out is float* (reference output dtype is float32);
// writing bf16 into it made the checker read bf16-pairs as f32 -> the
// invariant 4.6875 error across three independent pipelines. Inputs are f32
// (r1-r3 NaN = f32 read as bf16).
// Pipeline (fast path, restored from r4; numerics certified by r4==r5==r6):
//   0) cast (grid.z=5): x, Wq, Wk, Wv, Wo  f32 -> bf16 workspace copies
//   1) gemm_bt<bf16> (grid.z=3): Q,K,V = x @ W{q,k,v}^T    [4096x2048] bf16
//   2) rope: in-place RoPE on Q and K (position == row index)
//   3) vtrans: V -> Vt [b][h][128][2048] (Vt in low half of d_out scratch,
//      fully overwritten by step 5's f32 stores)
//   4) attn: flash MFMA attention -> Ab (aliases Vb; Vb dead after 3)
//   5) gemm_bt<float> (grid.z=1): out = Ab @ Wo^T -> d_out (f32 stores)
// Workspace: xb 16.78 + 4*Wb 33.55 + Q/K/V 50.33 = 100.7 MB.
// ---------------------------------------------------------------------------

#define AS1 __attribute__((address_space(1)))
#define AS3 __attribute__((address_space(3)))

typedef __bf16 bf16;
typedef float f32x4 __attribute__((ext_vector_type(4)));
typedef bf16 bf16x8 __attribute__((ext_vector_type(8)));
typedef bf16 bf16x4 __attribute__((ext_vector_type(4)));
typedef bf16 bf16x2 __attribute__((ext_vector_type(2)));

#define SEQ 2048
#define DMODEL 2048
#define NH 16
#define DK 128

// ---------------------------------------------------------------------------
// Cast f32 -> bf16.  z=0: x (8.4M elems);  z=1..4: weights (4.19M each).
// ---------------------------------------------------------------------------
__global__ __launch_bounds__(256) void cast_f32_bf16(
    const float* __restrict__ s0, const float* __restrict__ s1,
    const float* __restrict__ s2, const float* __restrict__ s3,
    const float* __restrict__ s4,
    bf16* __restrict__ d0, bf16* __restrict__ d1, bf16* __restrict__ d2,
    bf16* __restrict__ d3, bf16* __restrict__ d4)
{
    const int z = blockIdx.z;
    const float* s = (z == 0) ? s0 : (z == 1) ? s1 : (z == 2) ? s2 : (z == 3) ? s3 : s4;
    bf16*        d = (z == 0) ? d0 : (z == 1) ? d1 : (z == 2) ? d2 : (z == 3) ? d3 : d4;
    const int n = (z == 0) ? (4096 * 2048) : (2048 * 2048);
    const int i = (blockIdx.x * 256 + threadIdx.x) * 4;
    if (i >= n) return;
    const f32x4 v = *(const f32x4*)(s + i);
    bf16x4 r;
    r[0] = (bf16)v[0]; r[1] = (bf16)v[1]; r[2] = (bf16)v[2]; r[3] = (bf16)v[3];
    *(bf16x4*)(d + i) = r;
}

// ---------------------------------------------------------------------------
// GEMM: C = A @ B^T.  A [M][K] bf16, B [N][K] bf16, C [M][N] of type CT.
// 128x128 block tile, BK=32, 4 waves in 2x2, each wave 4x4 16x16x32 MFMA.
// m97 structure: global_load_lds width=16 staging, unpadded [128][32] LDS.
// Verified layouts: A-frag  A[m=lane&15][k=quad*8+j]
//                   B-frag  B^T[n=lane&15][k=quad*8+j]
//                   C/D     row=quad*4+reg, col=lane&15
// ---------------------------------------------------------------------------
template <typename CT>
__global__ __launch_bounds__(256, 2) void gemm_bt(
    const bf16* __restrict__ A,
    const bf16* __restrict__ B0, const bf16* __restrict__ B1, const bf16* __restrict__ B2,
    CT* __restrict__ C0, CT* __restrict__ C1, CT* __restrict__ C2,
    int M, int N, int K)
{
    const bf16* B = (blockIdx.z == 0) ? B0 : ((blockIdx.z == 1) ? B1 : B2);
    CT* C = (blockIdx.z == 0) ? C0 : ((blockIdx.z == 1) ? C1 : C2);

    __shared__ __align__(16) bf16 sA[128 * 32];
    __shared__ __align__(16) bf16 sB[128 * 32];

    const int tid  = threadIdx.x;
    const int m0   = blockIdx.y * 128;
    const int n0   = blockIdx.x * 128;
    const int lane = tid & 63;
    const int wave = tid >> 6;
    const int wr   = (wave >> 1) * 64;
    const int wc   = (wave & 1) * 64;
    const int l16  = lane & 15;
    const int quad = lane >> 4;

    f32x4 acc[4][4] = {};

    const int rowS = tid >> 2;
    const int c8   = (tid & 3) * 8;
    const bf16* gA = A + (m0 + rowS) * K + c8;
    const bf16* gB = B + (n0 + rowS) * K + c8;
    AS3 bf16* lA = (AS3 bf16*)sA + tid * 8;
    AS3 bf16* lB = (AS3 bf16*)sB + tid * 8;

    for (int k0 = 0; k0 < K; k0 += 32) {
        __syncthreads();
        __builtin_amdgcn_global_load_lds((const AS1 void*)(gA + k0),          (AS3 void*)lA,          16, 0, 0);
        __builtin_amdgcn_global_load_lds((const AS1 void*)(gA + 64 * K + k0), (AS3 void*)(lA + 2048), 16, 0, 0);
        __builtin_amdgcn_global_load_lds((const AS1 void*)(gB + k0),          (AS3 void*)lB,          16, 0, 0);
        __builtin_amdgcn_global_load_lds((const AS1 void*)(gB + 64 * K + k0), (AS3 void*)(lB + 2048), 16, 0, 0);
        __syncthreads();

        bf16x8 a[4], b[4];
#pragma unroll
        for (int t = 0; t < 4; t++)
            a[t] = *(const bf16x8*)(sA + (wr + t * 16 + l16) * 32 + quad * 8);
#pragma unroll
        for (int t = 0; t < 4; t++)
            b[t] = *(const bf16x8*)(sB + (wc + t * 16 + l16) * 32 + quad * 8);
#pragma unroll
        for (int i = 0; i < 4; i++)
#pragma unroll
            for (int j = 0; j < 4; j++)
                acc[i][j] = __builtin_amdgcn_mfma_f32_16x16x32_bf16(a[i], b[j], acc[i][j], 0, 0, 0);
    }

#pragma unroll
    for (int i = 0; i < 4; i++) {
        const int r0 = m0 + wr + i * 16 + quad * 4;
#pragma unroll
        for (int j = 0; j < 4; j++) {
            const int c = n0 + wc + j * 16 + l16;
#pragma unroll
            for (int r = 0; r < 4; r++)
                C[(size_t)(r0 + r) * N + c] = (CT)acc[i][j][r];
        }
    }
}

// ---------------------------------------------------------------------------
// RoPE in-place on Q and K.  One thread per (tensor, row, pair).
// pair pr = h*64 + p; cols 2pr, 2pr+1; phase = s * 10000^(-p/64).
// ---------------------------------------------------------------------------
__global__ __launch_bounds__(256) void rope_kernel(bf16* __restrict__ Q,
                                                   bf16* __restrict__ K)
{
    const int idx = blockIdx.x * 256 + threadIdx.x;
    const int pr  = idx & 1023;
    const int row = (idx >> 10) & 4095;
    const int t   = idx >> 22;
    bf16* P = t ? K : Q;
    const int s = row & (SEQ - 1);
    const int p = pr & 63;

    // log2(10000)/64 = 0.20762050593046836
    const float ph = (float)s * exp2f(-(float)p * 0.20762050593046836f);
    float sn, cs;
    sincosf(ph, &sn, &cs);

    bf16* ptr = P + row * DMODEL + pr * 2;
    bf16x2 v = *(const bf16x2*)ptr;
    const float x1 = (float)v[0], x2 = (float)v[1];
    bf16x2 r;
    r[0] = (bf16)(x1 * cs - x2 * sn);
    r[1] = (bf16)(x1 * sn + x2 * cs);
    *(bf16x2*)ptr = r;
}

// ---------------------------------------------------------------------------
// V transpose: V [b*S+s][h*128+d] -> Vt [(b*16+h)*128+d][s]
// ---------------------------------------------------------------------------
__global__ __launch_bounds__(256) void vtrans(const bf16* __restrict__ V,
                                              bf16* __restrict__ Vt)
{
    __shared__ bf16 t[32][33];
    const int bh = blockIdx.z;
    const int s0 = blockIdx.x * 32;
    const int d0 = blockIdx.y * 32;
    const int b = bh >> 4, h = bh & 15;
    const int tx = threadIdx.x & 31, ty = threadIdx.x >> 5;

#pragma unroll
    for (int i = 0; i < 4; i++) {
        const int s = s0 + ty + i * 8;
        t[ty + i * 8][tx] = V[(size_t)(b * SEQ + s) * DMODEL + h * DK + d0 + tx];
    }
    __syncthreads();
#pragma unroll
    for (int i = 0; i < 4; i++) {
        const int d = d0 + ty + i * 8;
        Vt[(size_t)(bh * DK + d) * SEQ + s0 + tx] = t[tx][ty + i * 8];
    }
}

// ---------------------------------------------------------------------------
// Flash-style causal MFMA attention (r4 structure, numerics certified vs
// naive by bit-identical downstream error r4==r5).
// Block = 4 waves; block owns (b, h, 64 q-rows); each wave owns 16 q-rows.
// ---------------------------------------------------------------------------
#define NEG 3.0e4f

__global__ __launch_bounds__(256, 2) void attn(
    const bf16* __restrict__ Q, const bf16* __restrict__ K,
    const bf16* __restrict__ Vt, bf16* __restrict__ O)
{
    const int qt = blockIdx.x, h = blockIdx.y, b = blockIdx.z;
    const int tid = threadIdx.x, lane = tid & 63, wave = tid >> 6;
    const int l16 = lane & 15, quad = lane >> 4;

    __shared__ __align__(16) bf16 sK[32 * 136];
    __shared__ __align__(16) bf16 sV[128 * 40];
    __shared__ __align__(16) bf16 sP[4][16 * 40];

    const int q0 = qt * 64 + wave * 16;

    bf16x8 qf[4];
    const bf16* gQ = Q + (size_t)(b * SEQ + q0 + l16) * DMODEL + h * DK + quad * 8;
#pragma unroll
    for (int dc = 0; dc < 4; dc++) qf[dc] = *(const bf16x8*)(gQ + dc * 32);

    f32x4 o[8] = {};
    float mrow[4] = {-NEG, -NEG, -NEG, -NEG};
    float lrow[4] = {0.f, 0.f, 0.f, 0.f};

    const bf16* gK = K + (size_t)(b * SEQ) * DMODEL + h * DK;
    const bf16* gV = Vt + (size_t)((b * NH + h) * DK) * SEQ;

    const float scale = 0.12751744154470187f;  // (1/sqrt(128)) * log2(e)
    const int nkt = 2 * (qt + 1);

    for (int kt = 0; kt < nkt; kt++) {
        __syncthreads();
        {   // stage K tile [32][128] and Vt tile [128][32]
            int c = tid, r = c >> 4, cc = c & 15;
            *(bf16x8*)&sK[r * 136 + cc * 8] = *(const bf16x8*)(gK + (size_t)(kt * 32 + r) * DMODEL + cc * 8);
            c = tid + 256; r = c >> 4; cc = c & 15;
            *(bf16x8*)&sK[r * 136 + cc * 8] = *(const bf16x8*)(gK + (size_t)(kt * 32 + r) * DMODEL + cc * 8);
            c = tid; int d = c >> 2; cc = c & 3;
            *(bf16x8*)&sV[d * 40 + cc * 8] = *(const bf16x8*)(gV + (size_t)d * SEQ + kt * 32 + cc * 8);
            c = tid + 256; d = c >> 2; cc = c & 3;
            *(bf16x8*)&sV[d * 40 + cc * 8] = *(const bf16x8*)(gV + (size_t)d * SEQ + kt * 32 + cc * 8);
        }
        __syncthreads();

        if (kt * 32 <= q0 + 15) {   // wave-uniform causal skip
            f32x4 sa = {}, sb = {};
#pragma unroll
            for (int dc = 0; dc < 4; dc++) {
                bf16x8 kb = *(const bf16x8*)(sK + l16 * 136 + dc * 32 + quad * 8);
                sa = __builtin_amdgcn_mfma_f32_16x16x32_bf16(qf[dc], kb, sa, 0, 0, 0);
            }
#pragma unroll
            for (int dc = 0; dc < 4; dc++) {
                bf16x8 kb = *(const bf16x8*)(sK + (16 + l16) * 136 + dc * 32 + quad * 8);
                sb = __builtin_amdgcn_mfma_f32_16x16x32_bf16(qf[dc], kb, sb, 0, 0, 0);
            }
            const int keyA = kt * 32 + l16;
            const int keyB = keyA + 16;
#pragma unroll
            for (int r = 0; r < 4; r++) {
                const int qg = q0 + quad * 4 + r;
                float va = (keyA <= qg) ? sa[r] * scale : -NEG;
                float vb = (keyB <= qg) ? sb[r] * scale : -NEG;
                float mx = fmaxf(va, vb);
#pragma unroll
                for (int d = 1; d < 16; d <<= 1) mx = fmaxf(mx, __shfl_xor(mx, d));
                const float mnew  = fmaxf(mrow[r], mx);
                const float alpha = exp2f(mrow[r] - mnew);
                const float pa = exp2f(va - mnew);
                const float pb = exp2f(vb - mnew);
                float ps = pa + pb;
#pragma unroll
                for (int d = 1; d < 16; d <<= 1) ps += __shfl_xor(ps, d);
                lrow[r] = lrow[r] * alpha + ps;
                mrow[r] = mnew;
#pragma unroll
                for (int dt = 0; dt < 8; dt++) o[dt][r] *= alpha;
                sP[wave][(quad * 4 + r) * 40 + l16]      = (bf16)pa;
                sP[wave][(quad * 4 + r) * 40 + 16 + l16] = (bf16)pb;
            }
            asm volatile("s_waitcnt lgkmcnt(0)" ::: "memory");

            const bf16x8 pf = *(const bf16x8*)(&sP[wave][l16 * 40 + quad * 8]);
#pragma unroll
            for (int dt = 0; dt < 8; dt++) {
                bf16x8 vf = *(const bf16x8*)(sV + (dt * 16 + l16) * 40 + quad * 8);
                o[dt] = __builtin_amdgcn_mfma_f32_16x16x32_bf16(pf, vf, o[dt], 0, 0, 0);
            }
        }
    }

    bf16* gO = O + (size_t)(b * SEQ + q0 + quad * 4) * DMODEL + h * DK + l16;
#pragma unroll
    for (int dt = 0; dt < 8; dt++)
#pragma unroll
        for (int r = 0; r < 4; r++)
            gO[(size_t)r * DMODEL + dt * 16] = (bf16)(o[dt][r] / lrow[r]);
}

// ---------------------------------------------------------------------------
extern "C" void kernel_launch(void* const* d_in, const int* in_sizes, int n_in,
                              void* d_out, int out_size, void* d_ws, size_t ws_size,
                              hipStream_t stream)
{
    const float* x  = (const float*)d_in[0];
    const float* Wq = (const float*)d_in[2];
    const float* Wk = (const float*)d_in[3];
    const float* Wv = (const float*)d_in[4];
    const float* Wo = (const float*)d_in[5];

    const int M = 2 * SEQ;       // 4096
    const int N = DMODEL;        // 2048
    const int Kd = DMODEL;       // 2048
    const size_t tsz = (size_t)M * N;   // 8.4M elems
    const size_t wsz = (size_t)N * Kd;  // 4.2M elems

    // Workspace layout (bf16): xb | Wqb Wkb Wvb Wob | Qb Kb Vb  = 100.7 MB
    bf16* xb  = (bf16*)d_ws;
    bf16* Wqb = xb  + tsz;
    bf16* Wkb = Wqb + wsz;
    bf16* Wvb = Wkb + wsz;
    bf16* Wob = Wvb + wsz;
    bf16* Qb  = Wob + wsz;
    bf16* Kb  = Qb  + tsz;
    bf16* Vb  = Kb  + tsz;
    bf16* Vt  = (bf16*)d_out;    // scratch in d_out (33.5 MB as f32); fully
                                 // overwritten by the final f32 GEMM stores
    bf16* Ab  = Vb;              // alias: Vb dead once Vt is built

    // 0) cast all f32 inputs to bf16
    cast_f32_bf16<<<dim3(tsz / 1024, 1, 5), 256, 0, stream>>>(
        x, Wq, Wk, Wv, Wo, xb, Wqb, Wkb, Wvb, Wob);

    // 1) Q,K,V projections (fused via grid.z), bf16 outputs
    gemm_bt<bf16><<<dim3(N / 128, M / 128, 3), 256, 0, stream>>>(
        xb, Wqb, Wkb, Wvb, Qb, Kb, Vb, M, N, Kd);

    // 2) RoPE on Q and K
    rope_kernel<<<(2 * 4096 * 1024) / 256, 256, 0, stream>>>(Qb, Kb);

    // 3) transpose V per (b,h) into d_out scratch
    vtrans<<<dim3(SEQ / 32, DK / 32, 2 * NH), 256, 0, stream>>>(Vb, Vt);

    // 4) causal flash attention -> Ab (Vb's storage)
    attn<<<dim3(SEQ / 64, NH, 2), 256, 0, stream>>>(Qb, Kb, Vt, Ab);

    // 5) output projection -> d_out, FLOAT32 stores (reference output dtype)
    gemm_bt<float><<<dim3(N / 128, M / 128, 1), 256, 0, stream>>>(
        Ab, Wob, Wob, Wob, (float*)d_out, (float*)d_out, (float*)d_out, M, N, Kd);
}